// Round 12
// baseline (60.627 us; speedup 1.0000x reference)
//
#include <hip/hip_runtime.h>

#define NPIX 16384
#define WIDTH 128
#define RPT 8                // rows per thread
#define CPT 8                // cols per thread
#define BROWS 256            // rows per block (32 tr-groups * 8)
#define TCOLS 64             // cols per tile (8 tc-groups * 8)
#define NT 8                 // tiles per block
#define BCOLS (TCOLS * NT)   // 512 cols per block
#define RBLK (NPIX / BROWS)  // 64 row-blocks
#define CBLK (NPIX / BCOLS)  // 32 col-blocks

__device__ __forceinline__ float min3f(float a, float b, float c) {
    float d;
    asm("v_min3_f32 %0, %1, %2, %3" : "=v"(d) : "v"(a), "v"(b), "v"(c));
    return d;
}

// depth -> (x, y, z, |p|^2 + inf_add). Same math as reference pixel2xyz.
__device__ __forceinline__ float4 make_point(float d, int p,
    float fu, float cu, float p03, float fv, float cv, float p13, float p23,
    float inf_add) {
    float px = (float)(p & (WIDTH - 1));
    float py = (float)(p >> 7);
    float x = (px * (d + p23) - (cu * d + p03)) / fu;
    float y = (py * (d + p23) - (cv * d + p13)) / fv;
    float s = x * x + y * y + d * d;
    return make_float4(x, y, d, s + inf_add);
}

// ---------------------------------------------------------------------------
// ONE-PASS chamfer kernel, atomic-free merges (R11 lesson: LDS atomicMin =
// 8.26M conflict cycles from same-address RMW serialization).
//   row-min merge: the 8 threads sharing a row differ only in lane bits 0-2
//     -> __shfl_xor 1/2/4 + fminf, once per block, no LDS.
//   col-min merge: per tile, __shfl_xor 8/16/32 merges the 8 tr-groups of a
//     wave; lanes 0-7 write non-atomic slots colPart[wave][...]; one 4-way
//     min at block end folds the waves. Every LDS slot written by exactly
//     one thread -> deterministic, conflict-free.
// f carries aw(+inf invalid row) + bw(+inf invalid col): both min directions
// fully masked, no add-back. 5 VALU slots per unique pair.
// ---------------------------------------------------------------------------
__global__ __launch_bounds__(256, 6) void pair_min_kernel(
    const float* __restrict__ pred,
    const float* __restrict__ target,
    const float* __restrict__ P,
    float* __restrict__ rowpm,
    float* __restrict__ colpm) {
    float fu = P[0], cu = P[2], p03 = P[3];
    float fv = P[5], cv = P[6], p13 = P[7], p23 = P[11];

    int t = threadIdx.x;
    int lane = t & 63, wv = t >> 6;
    int tr = t >> 3, tc = t & 7;
    int rb = blockIdx.x, cb = blockIdx.y;

    __shared__ alignas(16) float sBx[TCOLS], sBy[TCOLS], sBz[TCOLS], sBw[TCOLS];
    __shared__ float colPart[4][BCOLS];

    // A-state: 8 rows (target cloud), -2 folded, w carries A-side inf mask.
    int rowbase = rb * BROWS + tr * RPT;
    float ax[RPT], ay[RPT], az[RPT], aw[RPT], mn[RPT];
    #pragma unroll
    for (int r = 0; r < RPT; ++r) {
        int row = rowbase + r;
        float dt = target[row];
        float inf_add = (dt > 0.0f) ? 0.0f : 1e30f;
        float4 pa = make_point(dt, row, fu, cu, p03, fv, cv, p13, p23, inf_add);
        ax[r] = -2.0f * pa.x;
        ay[r] = -2.0f * pa.y;
        az[r] = -2.0f * pa.z;
        aw[r] = pa.w;
        mn[r] = 3e38f;
    }

    for (int ti = 0; ti < NT; ++ti) {
        __syncthreads();
        if (t < TCOLS) {
            int col = cb * BCOLS + ti * TCOLS + t;
            float tb = target[col];
            float inf_add = (tb > 0.0f) ? 0.0f : 1e30f;
            float4 b = make_point(pred[col], col, fu, cu, p03, fv, cv, p13, p23, inf_add);
            sBx[t] = b.x; sBy[t] = b.y; sBz[t] = b.z; sBw[t] = b.w;
        }
        __syncthreads();

        // per-thread 8 cols into registers (b128 LDS reads, 2-way aliasing = free)
        int base = tc * CPT;
        float bx[CPT], by[CPT], bz[CPT], bw[CPT], cp[CPT];
        {
            float4 x0 = *(const float4*)&sBx[base], x1 = *(const float4*)&sBx[base + 4];
            float4 y0 = *(const float4*)&sBy[base], y1 = *(const float4*)&sBy[base + 4];
            float4 z0 = *(const float4*)&sBz[base], z1 = *(const float4*)&sBz[base + 4];
            float4 w0 = *(const float4*)&sBw[base], w1 = *(const float4*)&sBw[base + 4];
            bx[0]=x0.x; bx[1]=x0.y; bx[2]=x0.z; bx[3]=x0.w; bx[4]=x1.x; bx[5]=x1.y; bx[6]=x1.z; bx[7]=x1.w;
            by[0]=y0.x; by[1]=y0.y; by[2]=y0.z; by[3]=y0.w; by[4]=y1.x; by[5]=y1.y; by[6]=y1.z; by[7]=y1.w;
            bz[0]=z0.x; bz[1]=z0.y; bz[2]=z0.z; bz[3]=z0.w; bz[4]=z1.x; bz[5]=z1.y; bz[6]=z1.z; bz[7]=z1.w;
            bw[0]=w0.x; bw[1]=w0.y; bw[2]=w0.z; bw[3]=w0.w; bw[4]=w1.x; bw[5]=w1.y; bw[6]=w1.z; bw[7]=w1.w;
        }
        #pragma unroll
        for (int c = 0; c < CPT; ++c) cp[c] = 3e38f;

        #pragma unroll
        for (int c = 0; c < CPT; c += 2) {
            #pragma unroll
            for (int r = 0; r < RPT; r += 2) {
                float f00 = aw[r]     + fmaf(ax[r],     bx[c],     fmaf(ay[r],     by[c],     fmaf(az[r],     bz[c],     bw[c])));
                float f01 = aw[r]     + fmaf(ax[r],     bx[c + 1], fmaf(ay[r],     by[c + 1], fmaf(az[r],     bz[c + 1], bw[c + 1])));
                float f10 = aw[r + 1] + fmaf(ax[r + 1], bx[c],     fmaf(ay[r + 1], by[c],     fmaf(az[r + 1], bz[c],     bw[c])));
                float f11 = aw[r + 1] + fmaf(ax[r + 1], bx[c + 1], fmaf(ay[r + 1], by[c + 1], fmaf(az[r + 1], bz[c + 1], bw[c + 1])));
                mn[r]     = min3f(f00, f01, mn[r]);
                mn[r + 1] = min3f(f10, f11, mn[r + 1]);
                cp[c]     = min3f(f00, f10, cp[c]);
                cp[c + 1] = min3f(f01, f11, cp[c + 1]);
            }
        }

        // col merge across the wave's 8 tr-groups (lane bits 3-5), then one
        // non-atomic LDS write per (wave, col).
        #pragma unroll
        for (int c = 0; c < CPT; ++c) {
            float v = cp[c];
            v = fminf(v, __shfl_xor(v, 8));
            v = fminf(v, __shfl_xor(v, 16));
            v = fminf(v, __shfl_xor(v, 32));
            cp[c] = v;
        }
        if (lane < 8) {
            #pragma unroll
            for (int c = 0; c < CPT; ++c)
                colPart[wv][ti * TCOLS + lane * CPT + c] = cp[c];
        }
    }

    // row merge across tc (lane bits 0-2), once per block.
    #pragma unroll
    for (int r = 0; r < RPT; ++r) {
        float v = mn[r];
        v = fminf(v, __shfl_xor(v, 1));
        v = fminf(v, __shfl_xor(v, 2));
        v = fminf(v, __shfl_xor(v, 4));
        mn[r] = v;
    }
    if (tc == 0) {
        #pragma unroll
        for (int r = 0; r < RPT; ++r)
            rowpm[cb * NPIX + rowbase + r] = mn[r];
    }

    __syncthreads();
    // fold the 4 wave-partials per col; each col written by exactly one thread.
    {
        float c0 = fminf(fminf(colPart[0][t],       colPart[1][t]),
                         fminf(colPart[2][t],       colPart[3][t]));
        float c1 = fminf(fminf(colPart[0][t + 256], colPart[1][t + 256]),
                         fminf(colPart[2][t + 256], colPart[3][t + 256]));
        colpm[rb * NPIX + cb * BCOLS + t]       = c0;
        colpm[rb * NPIX + cb * BCOLS + 256 + t] = c1;
    }
}

// ---------------------------------------------------------------------------
// Reduce: per pixel, min over 32 row-partials (dist12) and 64 col-partials
// (dist21) — no add-back (f carried |a|^2 and |b|^2). Masked fixed-order sum.
// ---------------------------------------------------------------------------
__global__ __launch_bounds__(256) void reduce_kernel(
    const float* __restrict__ rowpm,
    const float* __restrict__ colpm,
    const float* __restrict__ target,
    float* __restrict__ bsum,
    float* __restrict__ bn) {
    int t = threadIdx.x;
    int al = t & 63, q = t >> 6;
    int a = blockIdx.x * 64 + al;

    float d12 = 3e38f, d21 = 3e38f;
    for (int cb = q * (CBLK / 4); cb < (q + 1) * (CBLK / 4); ++cb)
        d12 = fminf(d12, rowpm[cb * NPIX + a]);
    for (int rbk = q * (RBLK / 4); rbk < (q + 1) * (RBLK / 4); ++rbk)
        d21 = fminf(d21, colpm[rbk * NPIX + a]);

    __shared__ float s12[4][64], s21[4][64];
    s12[q][al] = d12;
    s21[q][al] = d21;
    __syncthreads();

    if (t < 64) {
        d12 = fminf(fminf(s12[0][t], s12[1][t]), fminf(s12[2][t], s12[3][t]));
        d21 = fminf(fminf(s21[0][t], s21[1][t]), fminf(s21[2][t], s21[3][t]));
        float v = (target[a] > 0.0f) ? 1.0f : 0.0f;
        float contrib = v * (d12 + d21);
        for (int o = 32; o > 0; o >>= 1) {
            contrib += __shfl_down(contrib, o);
            v += __shfl_down(v, o);
        }
        if (t == 0) {
            bsum[blockIdx.x] = contrib;
            bn[blockIdx.x] = v;
        }
    }
}

// ---------------------------------------------------------------------------
// Final: fixed-order lane-parallel sum of 256 partials (deterministic).
// ---------------------------------------------------------------------------
__global__ void final_kernel(const float* __restrict__ bsum,
                             const float* __restrict__ bn,
                             float* __restrict__ out) {
    int t = threadIdx.x; // 64 threads
    float s = 0.0f, n = 0.0f;
    for (int i = t; i < 256; i += 64) { s += bsum[i]; n += bn[i]; }
    for (int o = 32; o > 0; o >>= 1) {
        s += __shfl_down(s, o);
        n += __shfl_down(n, o);
    }
    if (t == 0) out[0] = s / n;
}

extern "C" void kernel_launch(void* const* d_in, const int* in_sizes, int n_in,
                              void* d_out, int out_size, void* d_ws, size_t ws_size,
                              hipStream_t stream) {
    const float* pred   = (const float*)d_in[0];
    const float* target = (const float*)d_in[1];
    const float* P      = (const float*)d_in[2];
    float* out = (float*)d_out;

    char* ws = (char*)d_ws;
    float* rowpm = (float*)ws;                              // CBLK*NPIX floats (2 MB)
    float* colpm = rowpm + (size_t)CBLK * NPIX;             // RBLK*NPIX floats (4 MB)
    float* bsum  = colpm + (size_t)RBLK * NPIX;             // 256
    float* bn    = bsum + 256;

    dim3 grid(RBLK, CBLK);   // (64, 32) = 2048 blocks
    pair_min_kernel<<<grid, 256, 0, stream>>>(pred, target, P, rowpm, colpm);

    reduce_kernel<<<dim3(NPIX / 64), 256, 0, stream>>>(rowpm, colpm, target, bsum, bn);
    final_kernel<<<1, 64, 0, stream>>>(bsum, bn, out);
}

// Round 13
// 55.380 us; speedup vs baseline: 1.0947x; 1.0947x over previous
//
#include <hip/hip_runtime.h>

#define NPIX 16384
#define WIDTH 128
#define RPT 8                // rows per thread
#define CPT 8                // cols per thread-group-iteration
#define BROWS 256            // rows per block
#define BCOLS 512            // cols per block (all staged in LDS at once)
#define NGI (BCOLS / 64)     // 8 col-group iterations (64 cols each)
#define RBLK (NPIX / BROWS)  // 64 row-blocks
#define CBLK (NPIX / BCOLS)  // 32 col-blocks

__device__ __forceinline__ float min3f(float a, float b, float c) {
    float d;
    asm("v_min3_f32 %0, %1, %2, %3" : "=v"(d) : "v"(a), "v"(b), "v"(c));
    return d;
}

// depth -> (x, y, z, |p|^2 + inf_add). Same math as reference pixel2xyz.
__device__ __forceinline__ float4 make_point(float d, int p,
    float fu, float cu, float p03, float fv, float cv, float p13, float p23,
    float inf_add) {
    float px = (float)(p & (WIDTH - 1));
    float py = (float)(p >> 7);
    float x = (px * (d + p23) - (cu * d + p03)) / fu;
    float y = (py * (d + p23) - (cv * d + p13)) / fv;
    float s = x * x + y * y + d * d;
    return make_float4(x, y, d, s + inf_add);
}

// ---------------------------------------------------------------------------
// ONE-PASS chamfer kernel. Each D entry computed once, feeding BOTH row-min
// and col-min (5 VALU slots per unique pair). All 512 cols staged in LDS SoA
// once -> ONE barrier pair (R11 had 16 barriers). Merges are atomic-free
// shuffle trees (R11 lesson: LDS atomicMin = 8.26M conflict cycles). ALL
// global stores are dense & coalesced (R12 lesson: scattered partial-line
// stores amplify HBM writes ~8x -> kernel went HBM-bound); row results pass
// through a tiny LDS rowBuf to regain coalescing. f carries aw(+inf invalid
// row) + bw(+inf invalid col): both directions fully masked, no add-back.
// ---------------------------------------------------------------------------
__global__ __launch_bounds__(256, 4) void pair_min_kernel(
    const float* __restrict__ pred,
    const float* __restrict__ target,
    const float* __restrict__ P,
    float* __restrict__ rowpm,
    float* __restrict__ colpm) {
    float fu = P[0], cu = P[2], p03 = P[3];
    float fv = P[5], cv = P[6], p13 = P[7], p23 = P[11];

    int t = threadIdx.x;
    int lane = t & 63, wv = t >> 6;
    int tr = t >> 3, tc = t & 7;
    int rb = blockIdx.x, cb = blockIdx.y;

    __shared__ alignas(16) float sBx[BCOLS], sBy[BCOLS], sBz[BCOLS], sBw[BCOLS];
    __shared__ float rowBuf[BROWS];
    __shared__ float colPart[4][BCOLS];

    // stage all 512 cols (2 per thread, coalesced reads, stride-1 LDS writes)
    #pragma unroll
    for (int i = t; i < BCOLS; i += 256) {
        int col = cb * BCOLS + i;
        float tb = target[col];
        float inf_add = (tb > 0.0f) ? 0.0f : 1e30f;
        float4 b = make_point(pred[col], col, fu, cu, p03, fv, cv, p13, p23, inf_add);
        sBx[i] = b.x; sBy[i] = b.y; sBz[i] = b.z; sBw[i] = b.w;
    }

    // A-state: 8 rows (target cloud), -2 folded, w carries A-side inf mask.
    int rowbase = rb * BROWS + tr * RPT;
    float ax[RPT], ay[RPT], az[RPT], aw[RPT], mn[RPT];
    #pragma unroll
    for (int r = 0; r < RPT; ++r) {
        int row = rowbase + r;
        float dt = target[row];
        float inf_add = (dt > 0.0f) ? 0.0f : 1e30f;
        float4 pa = make_point(dt, row, fu, cu, p03, fv, cv, p13, p23, inf_add);
        ax[r] = -2.0f * pa.x;
        ay[r] = -2.0f * pa.y;
        az[r] = -2.0f * pa.z;
        aw[r] = pa.w;
        mn[r] = 3e38f;
    }

    __syncthreads();

    for (int gi = 0; gi < NGI; ++gi) {
        // this thread's 8 cols for this group (b128 LDS reads, 8-lane broadcast)
        int base = gi * 64 + tc * CPT;
        float bx[CPT], by[CPT], bz[CPT], bw[CPT], cp[CPT];
        {
            float4 x0 = *(const float4*)&sBx[base], x1 = *(const float4*)&sBx[base + 4];
            float4 y0 = *(const float4*)&sBy[base], y1 = *(const float4*)&sBy[base + 4];
            float4 z0 = *(const float4*)&sBz[base], z1 = *(const float4*)&sBz[base + 4];
            float4 w0 = *(const float4*)&sBw[base], w1 = *(const float4*)&sBw[base + 4];
            bx[0]=x0.x; bx[1]=x0.y; bx[2]=x0.z; bx[3]=x0.w; bx[4]=x1.x; bx[5]=x1.y; bx[6]=x1.z; bx[7]=x1.w;
            by[0]=y0.x; by[1]=y0.y; by[2]=y0.z; by[3]=y0.w; by[4]=y1.x; by[5]=y1.y; by[6]=y1.z; by[7]=y1.w;
            bz[0]=z0.x; bz[1]=z0.y; bz[2]=z0.z; bz[3]=z0.w; bz[4]=z1.x; bz[5]=z1.y; bz[6]=z1.z; bz[7]=z1.w;
            bw[0]=w0.x; bw[1]=w0.y; bw[2]=w0.z; bw[3]=w0.w; bw[4]=w1.x; bw[5]=w1.y; bw[6]=w1.z; bw[7]=w1.w;
        }
        #pragma unroll
        for (int c = 0; c < CPT; ++c) cp[c] = 3e38f;

        #pragma unroll
        for (int c = 0; c < CPT; c += 2) {
            #pragma unroll
            for (int r = 0; r < RPT; r += 2) {
                float f00 = aw[r]     + fmaf(ax[r],     bx[c],     fmaf(ay[r],     by[c],     fmaf(az[r],     bz[c],     bw[c])));
                float f01 = aw[r]     + fmaf(ax[r],     bx[c + 1], fmaf(ay[r],     by[c + 1], fmaf(az[r],     bz[c + 1], bw[c + 1])));
                float f10 = aw[r + 1] + fmaf(ax[r + 1], bx[c],     fmaf(ay[r + 1], by[c],     fmaf(az[r + 1], bz[c],     bw[c])));
                float f11 = aw[r + 1] + fmaf(ax[r + 1], bx[c + 1], fmaf(ay[r + 1], by[c + 1], fmaf(az[r + 1], bz[c + 1], bw[c + 1])));
                mn[r]     = min3f(f00, f01, mn[r]);
                mn[r + 1] = min3f(f10, f11, mn[r + 1]);
                cp[c]     = min3f(f00, f10, cp[c]);
                cp[c + 1] = min3f(f01, f11, cp[c + 1]);
            }
        }

        // col merge across the wave's 8 tr-groups (lane bits 3-5); lanes 0-7
        // (tc==lane) then hold all 8 tc-groups -> one non-atomic write each.
        #pragma unroll
        for (int c = 0; c < CPT; ++c) {
            float v = cp[c];
            v = fminf(v, __shfl_xor(v, 8));
            v = fminf(v, __shfl_xor(v, 16));
            v = fminf(v, __shfl_xor(v, 32));
            cp[c] = v;
        }
        if (lane < 8) {
            #pragma unroll
            for (int c = 0; c < CPT; ++c)
                colPart[wv][gi * 64 + lane * CPT + c] = cp[c];
        }
    }

    // row merge across tc (lane bits 0-2) -> LDS rowBuf (2-way aliasing, free)
    #pragma unroll
    for (int r = 0; r < RPT; ++r) {
        float v = mn[r];
        v = fminf(v, __shfl_xor(v, 1));
        v = fminf(v, __shfl_xor(v, 2));
        v = fminf(v, __shfl_xor(v, 4));
        mn[r] = v;
    }
    if (tc == 0) {
        #pragma unroll
        for (int r = 0; r < RPT; ++r)
            rowBuf[tr * RPT + r] = mn[r];
    }

    __syncthreads();

    // ALL global stores dense & coalesced (R12 lesson).
    rowpm[cb * NPIX + rb * BROWS + t] = rowBuf[t];
    {
        float c0 = fminf(fminf(colPart[0][t],       colPart[1][t]),
                         fminf(colPart[2][t],       colPart[3][t]));
        float c1 = fminf(fminf(colPart[0][t + 256], colPart[1][t + 256]),
                         fminf(colPart[2][t + 256], colPart[3][t + 256]));
        colpm[rb * NPIX + cb * BCOLS + t]       = c0;
        colpm[rb * NPIX + cb * BCOLS + 256 + t] = c1;
    }
}

// ---------------------------------------------------------------------------
// Reduce: per pixel, min over 32 row-partials (dist12) and 64 col-partials
// (dist21) — no add-back (f carried |a|^2 and |b|^2). Masked fixed-order sum.
// ---------------------------------------------------------------------------
__global__ __launch_bounds__(256) void reduce_kernel(
    const float* __restrict__ rowpm,
    const float* __restrict__ colpm,
    const float* __restrict__ target,
    float* __restrict__ bsum,
    float* __restrict__ bn) {
    int t = threadIdx.x;
    int al = t & 63, q = t >> 6;
    int a = blockIdx.x * 64 + al;

    float d12 = 3e38f, d21 = 3e38f;
    for (int cb = q * (CBLK / 4); cb < (q + 1) * (CBLK / 4); ++cb)
        d12 = fminf(d12, rowpm[cb * NPIX + a]);
    for (int rbk = q * (RBLK / 4); rbk < (q + 1) * (RBLK / 4); ++rbk)
        d21 = fminf(d21, colpm[rbk * NPIX + a]);

    __shared__ float s12[4][64], s21[4][64];
    s12[q][al] = d12;
    s21[q][al] = d21;
    __syncthreads();

    if (t < 64) {
        d12 = fminf(fminf(s12[0][t], s12[1][t]), fminf(s12[2][t], s12[3][t]));
        d21 = fminf(fminf(s21[0][t], s21[1][t]), fminf(s21[2][t], s21[3][t]));
        float v = (target[a] > 0.0f) ? 1.0f : 0.0f;
        float contrib = v * (d12 + d21);
        for (int o = 32; o > 0; o >>= 1) {
            contrib += __shfl_down(contrib, o);
            v += __shfl_down(v, o);
        }
        if (t == 0) {
            bsum[blockIdx.x] = contrib;
            bn[blockIdx.x] = v;
        }
    }
}

// ---------------------------------------------------------------------------
// Final: fixed-order lane-parallel sum of 256 partials (deterministic).
// ---------------------------------------------------------------------------
__global__ void final_kernel(const float* __restrict__ bsum,
                             const float* __restrict__ bn,
                             float* __restrict__ out) {
    int t = threadIdx.x; // 64 threads
    float s = 0.0f, n = 0.0f;
    for (int i = t; i < 256; i += 64) { s += bsum[i]; n += bn[i]; }
    for (int o = 32; o > 0; o >>= 1) {
        s += __shfl_down(s, o);
        n += __shfl_down(n, o);
    }
    if (t == 0) out[0] = s / n;
}

extern "C" void kernel_launch(void* const* d_in, const int* in_sizes, int n_in,
                              void* d_out, int out_size, void* d_ws, size_t ws_size,
                              hipStream_t stream) {
    const float* pred   = (const float*)d_in[0];
    const float* target = (const float*)d_in[1];
    const float* P      = (const float*)d_in[2];
    float* out = (float*)d_out;

    char* ws = (char*)d_ws;
    float* rowpm = (float*)ws;                              // CBLK*NPIX floats (2 MB)
    float* colpm = rowpm + (size_t)CBLK * NPIX;             // RBLK*NPIX floats (4 MB)
    float* bsum  = colpm + (size_t)RBLK * NPIX;             // 256
    float* bn    = bsum + 256;

    dim3 grid(RBLK, CBLK);   // (64, 32) = 2048 blocks
    pair_min_kernel<<<grid, 256, 0, stream>>>(pred, target, P, rowpm, colpm);

    reduce_kernel<<<dim3(NPIX / 64), 256, 0, stream>>>(rowpm, colpm, target, bsum, bn);
    final_kernel<<<1, 64, 0, stream>>>(bsum, bn, out);
}

// Round 14
// 52.796 us; speedup vs baseline: 1.1483x; 1.0489x over previous
//
#include <hip/hip_runtime.h>

#define NPIX 16384
#define WIDTH 128
#define RPT 8                // rows per thread
#define CPT 8                // cols per thread-group-iteration
#define BROWS 256            // rows per block
#define BCOLS 512            // cols per block (all staged in LDS at once)
#define NGI (BCOLS / 64)     // 8 col-group iterations (64 cols each)
#define RBLK (NPIX / BROWS)  // 64 row-blocks
#define CBLK (NPIX / BCOLS)  // 32 col-blocks

__device__ __forceinline__ float min3f(float a, float b, float c) {
    float d;
    asm("v_min3_f32 %0, %1, %2, %3" : "=v"(d) : "v"(a), "v"(b), "v"(c));
    return d;
}

// depth -> (x, y, z, |p|^2 + inf_add). Same math as reference pixel2xyz.
__device__ __forceinline__ float4 make_point(float d, int p,
    float fu, float cu, float p03, float fv, float cv, float p13, float p23,
    float inf_add) {
    float px = (float)(p & (WIDTH - 1));
    float py = (float)(p >> 7);
    float x = (px * (d + p23) - (cu * d + p03)) / fu;
    float y = (py * (d + p23) - (cv * d + p13)) / fv;
    float s = x * x + y * y + d * d;
    return make_float4(x, y, d, s + inf_add);
}

// ---------------------------------------------------------------------------
// ONE-PASS chamfer kernel. Each D entry computed once, feeding BOTH row-min
// and col-min (5 VALU slots/unique pair). R13 lesson: __shfl_xor = ds_swizzle
// = DS PIPE — 192 swizzles/gi-loop made DS (~25us) co-bottleneck with VALU.
// R14: merge tree moved to VALU cross-lane ops (gfx950 v_permlane16/32_swap):
//   xor8  : ds_swizzle (no VALU equivalent)        8 swizzle/gi
//   xor16 : v_permlane16_swap_b32 + v_min          4+4 VALU/gi
//   xor32 : v_permlane32_swap_b32 + v_min          2+2 VALU/gi
// After the tree, F0 holds cols (tc*8+row), F1 cols (tc*8+row+4) fully merged
// over the wave's 8 tr-groups -> two masked LDS writes/gi. Atomic-free (R11),
// all global stores dense & coalesced (R12), one barrier pair (R13).
// ---------------------------------------------------------------------------
__global__ __launch_bounds__(256, 6) void pair_min_kernel(
    const float* __restrict__ pred,
    const float* __restrict__ target,
    const float* __restrict__ P,
    float* __restrict__ rowpm,
    float* __restrict__ colpm) {
    float fu = P[0], cu = P[2], p03 = P[3];
    float fv = P[5], cv = P[6], p13 = P[7], p23 = P[11];

    int t = threadIdx.x;
    int lane = t & 63, wv = t >> 6;
    int tr = t >> 3, tc = t & 7;
    int rb = blockIdx.x, cb = blockIdx.y;

    __shared__ alignas(16) float sBx[BCOLS], sBy[BCOLS], sBz[BCOLS], sBw[BCOLS];
    __shared__ float rowBuf[BROWS];
    __shared__ float colPart[4][BCOLS];

    // stage all 512 cols (2 per thread, coalesced reads, stride-1 LDS writes)
    #pragma unroll
    for (int i = t; i < BCOLS; i += 256) {
        int col = cb * BCOLS + i;
        float tb = target[col];
        float inf_add = (tb > 0.0f) ? 0.0f : 1e30f;
        float4 b = make_point(pred[col], col, fu, cu, p03, fv, cv, p13, p23, inf_add);
        sBx[i] = b.x; sBy[i] = b.y; sBz[i] = b.z; sBw[i] = b.w;
    }

    // A-state: 8 rows (target cloud), -2 folded, w carries A-side inf mask.
    int rowbase = rb * BROWS + tr * RPT;
    float ax[RPT], ay[RPT], az[RPT], aw[RPT], mn[RPT];
    #pragma unroll
    for (int r = 0; r < RPT; ++r) {
        int row = rowbase + r;
        float dt = target[row];
        float inf_add = (dt > 0.0f) ? 0.0f : 1e30f;
        float4 pa = make_point(dt, row, fu, cu, p03, fv, cv, p13, p23, inf_add);
        ax[r] = -2.0f * pa.x;
        ay[r] = -2.0f * pa.y;
        az[r] = -2.0f * pa.z;
        aw[r] = pa.w;
        mn[r] = 3e38f;
    }

    __syncthreads();

    for (int gi = 0; gi < NGI; ++gi) {
        // this thread's 8 cols for this group (b128 LDS reads, 2-way = free)
        int base = gi * 64 + tc * CPT;
        float bx[CPT], by[CPT], bz[CPT], bw[CPT], cp[CPT];
        {
            float4 x0 = *(const float4*)&sBx[base], x1 = *(const float4*)&sBx[base + 4];
            float4 y0 = *(const float4*)&sBy[base], y1 = *(const float4*)&sBy[base + 4];
            float4 z0 = *(const float4*)&sBz[base], z1 = *(const float4*)&sBz[base + 4];
            float4 w0 = *(const float4*)&sBw[base], w1 = *(const float4*)&sBw[base + 4];
            bx[0]=x0.x; bx[1]=x0.y; bx[2]=x0.z; bx[3]=x0.w; bx[4]=x1.x; bx[5]=x1.y; bx[6]=x1.z; bx[7]=x1.w;
            by[0]=y0.x; by[1]=y0.y; by[2]=y0.z; by[3]=y0.w; by[4]=y1.x; by[5]=y1.y; by[6]=y1.z; by[7]=y1.w;
            bz[0]=z0.x; bz[1]=z0.y; bz[2]=z0.z; bz[3]=z0.w; bz[4]=z1.x; bz[5]=z1.y; bz[6]=z1.z; bz[7]=z1.w;
            bw[0]=w0.x; bw[1]=w0.y; bw[2]=w0.z; bw[3]=w0.w; bw[4]=w1.x; bw[5]=w1.y; bw[6]=w1.z; bw[7]=w1.w;
        }
        #pragma unroll
        for (int c = 0; c < CPT; ++c) cp[c] = 3e38f;

        #pragma unroll
        for (int c = 0; c < CPT; c += 2) {
            #pragma unroll
            for (int r = 0; r < RPT; r += 2) {
                float f00 = aw[r]     + fmaf(ax[r],     bx[c],     fmaf(ay[r],     by[c],     fmaf(az[r],     bz[c],     bw[c])));
                float f01 = aw[r]     + fmaf(ax[r],     bx[c + 1], fmaf(ay[r],     by[c + 1], fmaf(az[r],     bz[c + 1], bw[c + 1])));
                float f10 = aw[r + 1] + fmaf(ax[r + 1], bx[c],     fmaf(ay[r + 1], by[c],     fmaf(az[r + 1], bz[c],     bw[c])));
                float f11 = aw[r + 1] + fmaf(ax[r + 1], bx[c + 1], fmaf(ay[r + 1], by[c + 1], fmaf(az[r + 1], bz[c + 1], bw[c + 1])));
                mn[r]     = min3f(f00, f01, mn[r]);
                mn[r + 1] = min3f(f10, f11, mn[r + 1]);
                cp[c]     = min3f(f00, f10, cp[c]);
                cp[c + 1] = min3f(f01, f11, cp[c + 1]);
            }
        }

        // --- col merge over the wave's 8 tr-groups (lane bits 3,4,5) ---
        // xor8: swizzle (all lanes valid after)
        #pragma unroll
        for (int c = 0; c < CPT; ++c)
            cp[c] = fminf(cp[c], __shfl_xor(cp[c], 8));
        // xor16: permlane16_swap pairs (VALU). After min, 16-lane rows hold:
        //   m01 = [v0(h0), v1(h0), v0(h1), v1(h1)] etc. (h = lane-bit-5 half)
        float m01 = cp[0], s01 = cp[1];
        asm("v_permlane16_swap_b32 %0, %1" : "+v"(m01), "+v"(s01));
        m01 = fminf(m01, s01);
        float m23 = cp[2], s23 = cp[3];
        asm("v_permlane16_swap_b32 %0, %1" : "+v"(m23), "+v"(s23));
        m23 = fminf(m23, s23);
        float m45 = cp[4], s45 = cp[5];
        asm("v_permlane16_swap_b32 %0, %1" : "+v"(m45), "+v"(s45));
        m45 = fminf(m45, s45);
        float m67 = cp[6], s67 = cp[7];
        asm("v_permlane16_swap_b32 %0, %1" : "+v"(m67), "+v"(s67));
        m67 = fminf(m67, s67);
        // xor32: permlane32_swap (VALU). F0 rows 0-3 = values 0-3; F1 = 4-7.
        float F0 = m01, G0 = m23;
        asm("v_permlane32_swap_b32 %0, %1" : "+v"(F0), "+v"(G0));
        F0 = fminf(F0, G0);
        float F1 = m45, G1 = m67;
        asm("v_permlane32_swap_b32 %0, %1" : "+v"(F1), "+v"(G1));
        F1 = fminf(F1, G1);

        // value c lives in 16-lane row c (F0) / c-4 (F1); col = gi*64+tc*8+c.
        if ((lane & 8) == 0) {
            int row = lane >> 4;
            colPart[wv][gi * 64 + tc * CPT + row]     = F0;
            colPart[wv][gi * 64 + tc * CPT + row + 4] = F1;
        }
    }

    // row merge across tc (lane bits 0-2) -> LDS rowBuf (once per block)
    #pragma unroll
    for (int r = 0; r < RPT; ++r) {
        float v = mn[r];
        v = fminf(v, __shfl_xor(v, 1));
        v = fminf(v, __shfl_xor(v, 2));
        v = fminf(v, __shfl_xor(v, 4));
        mn[r] = v;
    }
    if (tc == 0) {
        #pragma unroll
        for (int r = 0; r < RPT; ++r)
            rowBuf[tr * RPT + r] = mn[r];
    }

    __syncthreads();

    // ALL global stores dense & coalesced (R12 lesson).
    rowpm[cb * NPIX + rb * BROWS + t] = rowBuf[t];
    {
        float c0 = fminf(fminf(colPart[0][t],       colPart[1][t]),
                         fminf(colPart[2][t],       colPart[3][t]));
        float c1 = fminf(fminf(colPart[0][t + 256], colPart[1][t + 256]),
                         fminf(colPart[2][t + 256], colPart[3][t + 256]));
        colpm[rb * NPIX + cb * BCOLS + t]       = c0;
        colpm[rb * NPIX + cb * BCOLS + 256 + t] = c1;
    }
}

// ---------------------------------------------------------------------------
// Reduce: per pixel, min over 32 row-partials (dist12) and 64 col-partials
// (dist21) — no add-back (f carried |a|^2 and |b|^2). Masked fixed-order sum.
// ---------------------------------------------------------------------------
__global__ __launch_bounds__(256) void reduce_kernel(
    const float* __restrict__ rowpm,
    const float* __restrict__ colpm,
    const float* __restrict__ target,
    float* __restrict__ bsum,
    float* __restrict__ bn) {
    int t = threadIdx.x;
    int al = t & 63, q = t >> 6;
    int a = blockIdx.x * 64 + al;

    float d12 = 3e38f, d21 = 3e38f;
    for (int cb = q * (CBLK / 4); cb < (q + 1) * (CBLK / 4); ++cb)
        d12 = fminf(d12, rowpm[cb * NPIX + a]);
    for (int rbk = q * (RBLK / 4); rbk < (q + 1) * (RBLK / 4); ++rbk)
        d21 = fminf(d21, colpm[rbk * NPIX + a]);

    __shared__ float s12[4][64], s21[4][64];
    s12[q][al] = d12;
    s21[q][al] = d21;
    __syncthreads();

    if (t < 64) {
        d12 = fminf(fminf(s12[0][t], s12[1][t]), fminf(s12[2][t], s12[3][t]));
        d21 = fminf(fminf(s21[0][t], s21[1][t]), fminf(s21[2][t], s21[3][t]));
        float v = (target[a] > 0.0f) ? 1.0f : 0.0f;
        float contrib = v * (d12 + d21);
        for (int o = 32; o > 0; o >>= 1) {
            contrib += __shfl_down(contrib, o);
            v += __shfl_down(v, o);
        }
        if (t == 0) {
            bsum[blockIdx.x] = contrib;
            bn[blockIdx.x] = v;
        }
    }
}

// ---------------------------------------------------------------------------
// Final: fixed-order lane-parallel sum of 256 partials (deterministic).
// ---------------------------------------------------------------------------
__global__ void final_kernel(const float* __restrict__ bsum,
                             const float* __restrict__ bn,
                             float* __restrict__ out) {
    int t = threadIdx.x; // 64 threads
    float s = 0.0f, n = 0.0f;
    for (int i = t; i < 256; i += 64) { s += bsum[i]; n += bn[i]; }
    for (int o = 32; o > 0; o >>= 1) {
        s += __shfl_down(s, o);
        n += __shfl_down(n, o);
    }
    if (t == 0) out[0] = s / n;
}

extern "C" void kernel_launch(void* const* d_in, const int* in_sizes, int n_in,
                              void* d_out, int out_size, void* d_ws, size_t ws_size,
                              hipStream_t stream) {
    const float* pred   = (const float*)d_in[0];
    const float* target = (const float*)d_in[1];
    const float* P      = (const float*)d_in[2];
    float* out = (float*)d_out;

    char* ws = (char*)d_ws;
    float* rowpm = (float*)ws;                              // CBLK*NPIX floats (2 MB)
    float* colpm = rowpm + (size_t)CBLK * NPIX;             // RBLK*NPIX floats (4 MB)
    float* bsum  = colpm + (size_t)RBLK * NPIX;             // 256
    float* bn    = bsum + 256;

    dim3 grid(RBLK, CBLK);   // (64, 32) = 2048 blocks
    pair_min_kernel<<<grid, 256, 0, stream>>>(pred, target, P, rowpm, colpm);

    reduce_kernel<<<dim3(NPIX / 64), 256, 0, stream>>>(rowpm, colpm, target, bsum, bn);
    final_kernel<<<1, 64, 0, stream>>>(bsum, bn, out);
}